// Round 1
// baseline (514.415 us; speedup 1.0000x reference)
//
#include <hip/hip_runtime.h>
#include <hip/hip_bf16.h>

typedef __attribute__((ext_vector_type(8))) short short8;
typedef __attribute__((ext_vector_type(4))) float f32x4;

#define V_TAB 100001
#define B_N   4096

// ---------------------------------------------------------------------------
// Kernel 1: embedding gather + mean-pool  -> pooled bf16 [B][16][64]
// One block per batch row, 4 waves, each wave does 4 features; lane = emb dim.
// All 20 multi-hot gathers issued unconditionally (mask applied after) so the
// 20 loads overlap in one memory-latency window.
// ---------------------------------------------------------------------------
__global__ __launch_bounds__(256) void pool_kernel(
    const int* __restrict__ feats,        // [B][168]
    const float* __restrict__ tables,     // [16][100001][64]
    __hip_bfloat16* __restrict__ pooled)  // [B][16][64]
{
    const int b    = blockIdx.x;
    const int wave = threadIdx.x >> 6;
    const int lane = threadIdx.x & 63;
    const int* fr  = feats + b * 168;

    #pragma unroll
    for (int k = 0; k < 4; ++k) {
        const int f   = wave * 4 + k;
        const int off = (f >> 1) * 21 + (f & 1);     // specs: (1,20) pairs, stride 21
        const float* tab = tables + (size_t)f * (V_TAB * 64);
        float acc;
        if ((f & 1) == 0) {                          // single-hot; row 0 counts as zero
            const int idx = fr[off];
            const float v = tab[idx * 64 + lane];    // unconditional load
            acc = (idx != 0) ? v : 0.f;
        } else {                                     // 20-hot mean pool over nonzero
            int idxv = (lane < 20) ? fr[off + lane] : 0;
            int   idxs[20];
            float vals[20];
            #pragma unroll
            for (int j = 0; j < 20; ++j) {           // issue all gathers first
                idxs[j] = __shfl(idxv, j);
                vals[j] = tab[idxs[j] * 64 + lane];
            }
            acc = 0.f; int cnt = 0;
            #pragma unroll
            for (int j = 0; j < 20; ++j) {
                if (idxs[j] != 0) { acc += vals[j]; cnt++; }
            }
            acc *= 1.f / (float)(cnt > 0 ? cnt : 1);
        }
        pooled[(b * 16 + f) * 64 + lane] = __float2bfloat16(acc);
    }
}

// ---------------------------------------------------------------------------
// Kernel 2: W fp32 -> bf16, pre-swizzled into MFMA B-fragment streaming order:
//   Wsw[((((g*4+w)*8+nt)*8+ks)*64+lane)*8+j] = W[g][k][n]
//   n = w*128 + nt*16 + (lane&15);  k = ks*32 + (lane>>4)*8 + j
// ---------------------------------------------------------------------------
__global__ __launch_bounds__(256) void wprep_kernel(
    const float* __restrict__ W,          // [4][256][512]
    __hip_bfloat16* __restrict__ Wsw)     // 524288 bf16
{
    const int idx = blockIdx.x * 256 + threadIdx.x;   // grid 2048 -> 524288
    int rem = idx;
    const int j    = rem & 7;   rem >>= 3;
    const int lane = rem & 63;  rem >>= 6;
    const int ks   = rem & 7;   rem >>= 3;
    const int nt   = rem & 7;   rem >>= 3;
    const int w    = rem & 3;   rem >>= 2;
    const int g    = rem;
    const int n = w * 128 + nt * 16 + (lane & 15);
    const int kk = ks * 32 + (lane >> 4) * 8 + j;
    Wsw[idx] = __float2bfloat16(W[(g * 256 + kk) * 512 + n]);
}

// ---------------------------------------------------------------------------
// Kernel 3: per group g, C = cat @ W[g] + b  -> LayerNorm -> SiLU.
// Block = 32 rows of one group; 4 waves x 128 cols; K=256 in 8 steps of 32.
// mfma_f32_16x16x32_bf16, fragments loaded directly from global.
// A and B use the SAME k-within-step mapping so k-permutation detail cancels.
// ---------------------------------------------------------------------------
__global__ __launch_bounds__(256) void gemm_ln_silu(
    const __hip_bfloat16* __restrict__ pooled,  // [B][1024] (group g = cols 256g..)
    const __hip_bfloat16* __restrict__ Wsw,     // swizzled bf16 W
    const float* __restrict__ bias,             // [4][512]
    const float* __restrict__ gamma,            // [4][512]
    const float* __restrict__ beta,             // [4][512]
    float* __restrict__ out)                    // [B][4][512]
{
    const int g       = blockIdx.y;
    const int rowbase = blockIdx.x * 32;
    const int wave = threadIdx.x >> 6;
    const int lane = threadIdx.x & 63;
    const int l15  = lane & 15;
    const int lg   = lane >> 4;
    const int wcol = wave * 128;

    f32x4 acc[2][8];
    #pragma unroll
    for (int mt = 0; mt < 2; ++mt)
        #pragma unroll
        for (int nt = 0; nt < 8; ++nt) acc[mt][nt] = (f32x4){0.f, 0.f, 0.f, 0.f};

    const short* wbase = (const short*)Wsw + (((size_t)(g * 4 + wave) * 64) * 64 + lane) * 8;
    const short* abase = (const short*)pooled + (size_t)(rowbase + l15) * 1024 + g * 256 + lg * 8;

    #pragma unroll
    for (int ks = 0; ks < 8; ++ks) {
        const short8 a0 = *(const short8*)(abase + ks * 32);
        const short8 a1 = *(const short8*)(abase + 16 * 1024 + ks * 32);
        #pragma unroll
        for (int nt = 0; nt < 8; ++nt) {
            const short8 bf = *(const short8*)(wbase + (size_t)(nt * 8 + ks) * 64 * 8);
            acc[0][nt] = __builtin_amdgcn_mfma_f32_16x16x32_bf16(a0, bf, acc[0][nt], 0, 0, 0);
            acc[1][nt] = __builtin_amdgcn_mfma_f32_16x16x32_bf16(a1, bf, acc[1][nt], 0, 0, 0);
        }
    }

    // epilogue: bias add, then LayerNorm stats across the 512-wide row
    float gv[8], tv[8];
    #pragma unroll
    for (int nt = 0; nt < 8; ++nt) {
        const int col = wcol + nt * 16 + l15;
        const float bv = bias[g * 512 + col];
        gv[nt] = gamma[g * 512 + col];
        tv[nt] = beta[g * 512 + col];
        #pragma unroll
        for (int r = 0; r < 4; ++r) { acc[0][nt][r] += bv; acc[1][nt][r] += bv; }
    }

    __shared__ float red[32][4][2];   // [row][wave][sum, sumsq]
    #pragma unroll
    for (int mt = 0; mt < 2; ++mt)
        #pragma unroll
        for (int r = 0; r < 4; ++r) {
            float s = 0.f, q = 0.f;
            #pragma unroll
            for (int nt = 0; nt < 8; ++nt) { const float v = acc[mt][nt][r]; s += v; q += v * v; }
            #pragma unroll
            for (int m = 1; m < 16; m <<= 1) { s += __shfl_xor(s, m); q += __shfl_xor(q, m); }
            if (l15 == 0) {
                const int row = mt * 16 + lg * 4 + r;
                red[row][wave][0] = s;
                red[row][wave][1] = q;
            }
        }
    __syncthreads();

    __shared__ float mu_s[32], ri_s[32];
    if (threadIdx.x < 32) {
        const int row = threadIdx.x;
        const float s = red[row][0][0] + red[row][1][0] + red[row][2][0] + red[row][3][0];
        const float q = red[row][0][1] + red[row][1][1] + red[row][2][1] + red[row][3][1];
        const float mu  = s * (1.f / 512.f);
        const float var = q * (1.f / 512.f) - mu * mu;
        mu_s[row] = mu;
        ri_s[row] = rsqrtf(var + 1e-5f);
    }
    __syncthreads();

    #pragma unroll
    for (int mt = 0; mt < 2; ++mt)
        #pragma unroll
        for (int r = 0; r < 4; ++r) {
            const int row = mt * 16 + lg * 4 + r;
            const float mu = mu_s[row];
            const float ri = ri_s[row];
            float* orow = out + ((size_t)(rowbase + row) * 4 + g) * 512 + wcol;
            #pragma unroll
            for (int nt = 0; nt < 8; ++nt) {
                const float h  = acc[mt][nt][r];
                const float hn = (h - mu) * ri * gv[nt] + tv[nt];
                orow[nt * 16 + l15] = hn / (1.f + __expf(-hn));
            }
        }
}

// ---------------------------------------------------------------------------
extern "C" void kernel_launch(void* const* d_in, const int* in_sizes, int n_in,
                              void* d_out, int out_size, void* d_ws, size_t ws_size,
                              hipStream_t stream) {
    const int*   feats  = (const int*)d_in[0];
    const float* tables = (const float*)d_in[1];
    const float* W      = (const float*)d_in[2];
    const float* bias   = (const float*)d_in[3];
    const float* gamma  = (const float*)d_in[4];
    const float* beta   = (const float*)d_in[5];
    float* out = (float*)d_out;

    __hip_bfloat16* pooled = (__hip_bfloat16*)d_ws;                       // 8 MB
    __hip_bfloat16* Wsw    = (__hip_bfloat16*)((char*)d_ws + (size_t)B_N * 16 * 64 * 2);  // 1 MB

    pool_kernel<<<dim3(B_N), dim3(256), 0, stream>>>(feats, tables, pooled);
    wprep_kernel<<<dim3(2048), dim3(256), 0, stream>>>(W, Wsw);
    gemm_ln_silu<<<dim3(128, 4), dim3(256), 0, stream>>>(pooled, Wsw, bias, gamma, beta, out);
}

// Round 2
// 505.448 us; speedup vs baseline: 1.0177x; 1.0177x over previous
//
#include <hip/hip_runtime.h>
#include <hip/hip_bf16.h>

typedef __attribute__((ext_vector_type(8))) short short8;
typedef __attribute__((ext_vector_type(4))) float f32x4;

#define V_TAB 100001
#define B_N   4096

// ---------------------------------------------------------------------------
// Kernel 1: embedding gather + mean-pool  -> pooled bf16 [B][16][64]
// One WAVE per (sample, feature-pair): 1 single-hot + 1 multi-hot feature.
// All 21 gathers are independent chains (indices read as wave-uniform loads,
// no shfl), so they overlap in one HBM latency window. ~50 VGPRs -> high occ.
// ---------------------------------------------------------------------------
__global__ __launch_bounds__(256) void pool_kernel(
    const int* __restrict__ feats,        // [B][168]
    const float* __restrict__ tables,     // [16][100001][64]
    __hip_bfloat16* __restrict__ pooled)  // [B][16][64]
{
    const int b    = blockIdx.x;
    const int p    = blockIdx.y * 4 + (threadIdx.x >> 6);   // pair 0..7
    const int lane = threadIdx.x & 63;
    const int* fr  = feats + b * 168 + p * 21;              // [single, 20 multi]
    const float* tab_s = tables + (size_t)(2 * p) * (V_TAB * 64);
    const float* tab_m = tab_s + (size_t)(V_TAB * 64);

    // issue all 21 gathers; each chain is independent (idx load -> row load)
    const int idx_s = fr[0];
    const float v_s = tab_s[(size_t)idx_s * 64 + lane];

    int   idxs[20];
    float vals[20];
    #pragma unroll
    for (int j = 0; j < 20; ++j) idxs[j] = fr[1 + j];       // wave-uniform
    #pragma unroll
    for (int j = 0; j < 20; ++j) vals[j] = tab_m[(size_t)idxs[j] * 64 + lane];

    float acc = 0.f; int cnt = 0;
    #pragma unroll
    for (int j = 0; j < 20; ++j)
        if (idxs[j] != 0) { acc += vals[j]; ++cnt; }
    acc *= 1.f / (float)(cnt > 0 ? cnt : 1);

    __hip_bfloat16* orow = pooled + ((size_t)b * 16 + 2 * p) * 64;
    orow[lane]      = __float2bfloat16((idx_s != 0) ? v_s : 0.f);
    orow[64 + lane] = __float2bfloat16(acc);
}

// ---------------------------------------------------------------------------
// Kernel 2: W fp32 -> bf16 swizzled to MFMA B-fragment streaming order.
// Reads are fully coalesced (thread id == flat W index); the scattered 2 B
// writes land in L2 (Wsw is 1 MB) with byte-mask merging.
//   dst[(((g*4+w)*8+nt)*8+ks)*64 + lane)*8 + j] = W[g][kk][n]
//   n = w*128+nt*16+(lane&15);  kk = ks*32+(lane>>4)*8+j
// ---------------------------------------------------------------------------
__global__ __launch_bounds__(256) void wprep_kernel(
    const float* __restrict__ W,          // [4][256][512]
    __hip_bfloat16* __restrict__ Wsw)     // 524288 bf16
{
    const int idx = blockIdx.x * 256 + threadIdx.x;   // == flat (g,kk,n)
    const int n   = idx & 511;
    const int kk  = (idx >> 9) & 255;
    const int g   = idx >> 17;
    const int w   = n >> 7;
    const int nt  = (n >> 4) & 7;
    const int l15 = n & 15;
    const int ks  = kk >> 5;
    const int lg  = (kk >> 3) & 3;
    const int j   = kk & 7;
    const int lane = lg * 16 + l15;
    const int dst = ((((g * 4 + w) * 8 + nt) * 8 + ks) * 64 + lane) * 8 + j;
    Wsw[dst] = __float2bfloat16(W[idx]);
}

// ---------------------------------------------------------------------------
// Kernel 3: per group g, C = cat @ W[g] + b -> LayerNorm -> SiLU.
// Block = 32 rows; 4 waves x 128 cols; K=256 in 8 steps of 32.
// A tile staged in LDS (row-padded +16B to spread ds_read_b128 banks);
// B fragments stream from global (L2-resident) with a manual 1-deep
// double-buffer; #pragma unroll 1 on the K-loop to keep VGPRs ~160 (no spill).
// ---------------------------------------------------------------------------
__global__ __launch_bounds__(256, 2) void gemm_ln_silu(
    const __hip_bfloat16* __restrict__ pooled,  // [B][1024]
    const __hip_bfloat16* __restrict__ Wsw,     // swizzled bf16 W
    const float* __restrict__ bias,             // [4][512]
    const float* __restrict__ gamma,            // [4][512]
    const float* __restrict__ beta,             // [4][512]
    float* __restrict__ out)                    // [B][4][512]
{
    const int g       = blockIdx.y;
    const int rowbase = blockIdx.x * 32;
    const int wave = threadIdx.x >> 6;
    const int lane = threadIdx.x & 63;
    const int l15  = lane & 15;
    const int lg   = lane >> 4;
    const int wcol = wave * 128;

    // ---- stage A tile: 32 rows x 256 k (bf16), row stride 264 shorts ----
    __shared__ short lds_a[32 * 264];
    {
        const int r  = threadIdx.x >> 3;       // 0..31
        const int c0 = threadIdx.x & 7;        // chunk 0..7
        const short* src = (const short*)pooled + (size_t)(rowbase + r) * 1024 + g * 256;
        #pragma unroll
        for (int i = 0; i < 4; ++i) {
            const int c = c0 + i * 8;          // 16B chunk 0..31
            *(short8*)(lds_a + r * 264 + c * 8) = *(const short8*)(src + c * 8);
        }
    }
    __syncthreads();

    f32x4 acc[2][8];
    #pragma unroll
    for (int mt = 0; mt < 2; ++mt)
        #pragma unroll
        for (int nt = 0; nt < 8; ++nt) acc[mt][nt] = (f32x4){0.f, 0.f, 0.f, 0.f};

    const short* wptr = (const short*)Wsw + ((size_t)(g * 4 + wave) * 4096 + lane) * 8;

    short8 bcur[8], bnxt[8];
    #pragma unroll
    for (int nt = 0; nt < 8; ++nt)
        bcur[nt] = *(const short8*)(wptr + (size_t)(nt * 8) * 512);

    #pragma unroll 1
    for (int ks = 0; ks < 8; ++ks) {
        if (ks < 7) {
            #pragma unroll
            for (int nt = 0; nt < 8; ++nt)
                bnxt[nt] = *(const short8*)(wptr + (size_t)(nt * 8 + ks + 1) * 512);
        }
        const short8 a0 = *(const short8*)(lds_a + l15 * 264 + ks * 32 + lg * 8);
        const short8 a1 = *(const short8*)(lds_a + (16 + l15) * 264 + ks * 32 + lg * 8);
        #pragma unroll
        for (int nt = 0; nt < 8; ++nt) {
            acc[0][nt] = __builtin_amdgcn_mfma_f32_16x16x32_bf16(a0, bcur[nt], acc[0][nt], 0, 0, 0);
            acc[1][nt] = __builtin_amdgcn_mfma_f32_16x16x32_bf16(a1, bcur[nt], acc[1][nt], 0, 0, 0);
        }
        #pragma unroll
        for (int nt = 0; nt < 8; ++nt) bcur[nt] = bnxt[nt];
    }

    // ---- epilogue: bias, LN stats (cross-wave via LDS), SiLU, store ----
    float gv[8], tv[8];
    #pragma unroll
    for (int nt = 0; nt < 8; ++nt) {
        const int col = wcol + nt * 16 + l15;
        const float bv = bias[g * 512 + col];
        gv[nt] = gamma[g * 512 + col];
        tv[nt] = beta[g * 512 + col];
        #pragma unroll
        for (int r = 0; r < 4; ++r) { acc[0][nt][r] += bv; acc[1][nt][r] += bv; }
    }

    __shared__ float red[32][4][2];   // [row][wave][sum, sumsq]
    #pragma unroll
    for (int mt = 0; mt < 2; ++mt)
        #pragma unroll
        for (int r = 0; r < 4; ++r) {
            float s = 0.f, q = 0.f;
            #pragma unroll
            for (int nt = 0; nt < 8; ++nt) { const float v = acc[mt][nt][r]; s += v; q += v * v; }
            #pragma unroll
            for (int m = 1; m < 16; m <<= 1) { s += __shfl_xor(s, m); q += __shfl_xor(q, m); }
            if (l15 == 0) {
                const int row = mt * 16 + lg * 4 + r;
                red[row][wave][0] = s;
                red[row][wave][1] = q;
            }
        }
    __syncthreads();

    __shared__ float mu_s[32], ri_s[32];
    if (threadIdx.x < 32) {
        const int row = threadIdx.x;
        const float s = red[row][0][0] + red[row][1][0] + red[row][2][0] + red[row][3][0];
        const float q = red[row][0][1] + red[row][1][1] + red[row][2][1] + red[row][3][1];
        const float mu  = s * (1.f / 512.f);
        const float var = q * (1.f / 512.f) - mu * mu;
        mu_s[row] = mu;
        ri_s[row] = rsqrtf(var + 1e-5f);
    }
    __syncthreads();

    #pragma unroll
    for (int mt = 0; mt < 2; ++mt)
        #pragma unroll
        for (int r = 0; r < 4; ++r) {
            const int row = mt * 16 + lg * 4 + r;
            const float mu = mu_s[row];
            const float ri = ri_s[row];
            float* orow = out + ((size_t)(rowbase + row) * 4 + g) * 512 + wcol;
            #pragma unroll
            for (int nt = 0; nt < 8; ++nt) {
                const float h  = acc[mt][nt][r];
                const float hn = (h - mu) * ri * gv[nt] + tv[nt];
                orow[nt * 16 + l15] = hn / (1.f + __expf(-hn));
            }
        }
}

// ---------------------------------------------------------------------------
extern "C" void kernel_launch(void* const* d_in, const int* in_sizes, int n_in,
                              void* d_out, int out_size, void* d_ws, size_t ws_size,
                              hipStream_t stream) {
    const int*   feats  = (const int*)d_in[0];
    const float* tables = (const float*)d_in[1];
    const float* W      = (const float*)d_in[2];
    const float* bias   = (const float*)d_in[3];
    const float* gamma  = (const float*)d_in[4];
    const float* beta   = (const float*)d_in[5];
    float* out = (float*)d_out;

    __hip_bfloat16* pooled = (__hip_bfloat16*)d_ws;                                       // 8 MB
    __hip_bfloat16* Wsw    = (__hip_bfloat16*)((char*)d_ws + (size_t)B_N * 16 * 64 * 2);  // 1 MB

    pool_kernel<<<dim3(B_N, 2), dim3(256), 0, stream>>>(feats, tables, pooled);
    wprep_kernel<<<dim3(2048), dim3(256), 0, stream>>>(W, Wsw);
    gemm_ln_silu<<<dim3(128, 4), dim3(256), 0, stream>>>(pooled, Wsw, bias, gamma, beta, out);
}

// Round 4
// 500.034 us; speedup vs baseline: 1.0288x; 1.0108x over previous
//
#include <hip/hip_runtime.h>
#include <hip/hip_bf16.h>

typedef __attribute__((ext_vector_type(8))) short short8;
typedef __attribute__((ext_vector_type(4))) float f32x4;

#define V_TAB 100001
#define B_N   4096

// ---------------------------------------------------------------------------
// Kernel 1: W fp32 -> bf16 swizzled to MFMA B-fragment streaming order.
// Reads fully coalesced (thread id == flat W index); scattered 2 B writes
// land in L2 (Wsw is 1 MB).
//   dst[((((g*4+w)*8+nt)*8+ks)*64 + lane)*8 + j] = W[g][kk][n]
//   n = w*128+nt*16+(lane&15);  kk = ks*32+(lane>>4)*8+j
// ---------------------------------------------------------------------------
__global__ __launch_bounds__(256) void wprep_kernel(
    const float* __restrict__ W,          // [4][256][512]
    __hip_bfloat16* __restrict__ Wsw)     // 524288 bf16
{
    const int idx = blockIdx.x * 256 + threadIdx.x;   // == flat (g,kk,n)
    const int n   = idx & 511;
    const int kk  = (idx >> 9) & 255;
    const int g   = idx >> 17;
    const int w   = n >> 7;
    const int nt  = (n >> 4) & 7;
    const int l15 = n & 15;
    const int ks  = kk >> 5;
    const int lg  = (kk >> 3) & 3;
    const int j   = kk & 7;
    const int lane = lg * 16 + l15;
    const int dst = ((((g * 4 + w) * 8 + nt) * 8 + ks) * 64 + lane) * 8 + j;
    Wsw[dst] = __float2bfloat16(W[idx]);
}

// ---------------------------------------------------------------------------
// Kernel 2 (fused): per block = 32 rows x one group g.
//   Phase 1: gather+pool this block's 4 features (2 single + 2x20 multi)
//            straight into the LDS A-tile (bf16, row stride 264 shorts).
//            Wave w pools rows w*8..w*8+7; per row all 42 gathers are issued
//            as independent chains (BW-bound, latency hidden by 8 waves/CU).
//   Phase 2: C = A @ W[g] + b via mfma_f32_16x16x32_bf16 (B fragments stream
//            from swizzled L2-resident Wsw, 1-deep double buffer),
//            then LayerNorm (cross-wave LDS reduce) + SiLU.
// ---------------------------------------------------------------------------
__global__ __launch_bounds__(256, 2) void fused_pool_gemm_ln(
    const int* __restrict__ feats,              // [B][168]
    const float* __restrict__ tables,           // [16][100001][64]
    const __hip_bfloat16* __restrict__ Wsw,     // swizzled bf16 W
    const float* __restrict__ bias,             // [4][512]
    const float* __restrict__ gamma,            // [4][512]
    const float* __restrict__ beta,             // [4][512]
    float* __restrict__ out)                    // [B][4][512]
{
    const int g       = blockIdx.y;
    const int rowbase = blockIdx.x * 32;
    const int wave = threadIdx.x >> 6;
    const int lane = threadIdx.x & 63;
    const int l15  = lane & 15;
    const int lg   = lane >> 4;
    const int wcol = wave * 128;

    __shared__ short lds_a[32 * 264];           // A tile: [row][k], stride 264

    // ---- Phase 1: pool 8 rows per wave ----
    const size_t TSZ = (size_t)V_TAB * 64;
    const float* t0 = tables + (size_t)(4 * g) * TSZ;
    const float* t1 = t0 + TSZ;
    const float* t2 = t1 + TSZ;
    const float* t3 = t2 + TSZ;

    #pragma unroll 1
    for (int rr = 0; rr < 8; ++rr) {
        const int r = wave * 8 + rr;
        const int* fr = feats + (size_t)(rowbase + r) * 168 + g * 42;

        const int i0 = fr[0];
        const int i2 = fr[21];
        int idx1[20], idx3[20];
        #pragma unroll
        for (int j = 0; j < 20; ++j) { idx1[j] = fr[1 + j]; idx3[j] = fr[22 + j]; }

        // issue all 42 gathers as independent chains
        const float v0 = t0[(size_t)i0 * 64 + lane];
        const float v2 = t2[(size_t)i2 * 64 + lane];
        float v1[20], v3[20];
        #pragma unroll
        for (int j = 0; j < 20; ++j) {
            v1[j] = t1[(size_t)idx1[j] * 64 + lane];
            v3[j] = t3[(size_t)idx3[j] * 64 + lane];
        }

        float a1 = 0.f, a3 = 0.f; int c1 = 0, c3 = 0;
        #pragma unroll
        for (int j = 0; j < 20; ++j) {
            if (idx1[j] != 0) { a1 += v1[j]; ++c1; }
            if (idx3[j] != 0) { a3 += v3[j]; ++c3; }
        }
        a1 *= 1.f / (float)(c1 > 0 ? c1 : 1);
        a3 *= 1.f / (float)(c3 > 0 ? c3 : 1);

        short* arow = lds_a + r * 264;
        ((__hip_bfloat16*)arow)[lane]       = __float2bfloat16(i0 != 0 ? v0 : 0.f);
        ((__hip_bfloat16*)arow)[64 + lane]  = __float2bfloat16(a1);
        ((__hip_bfloat16*)arow)[128 + lane] = __float2bfloat16(i2 != 0 ? v2 : 0.f);
        ((__hip_bfloat16*)arow)[192 + lane] = __float2bfloat16(a3);
    }
    __syncthreads();

    // ---- Phase 2: GEMM (K=256 in 8 steps of 32) ----
    f32x4 acc[2][8];
    #pragma unroll
    for (int mt = 0; mt < 2; ++mt)
        #pragma unroll
        for (int nt = 0; nt < 8; ++nt) acc[mt][nt] = (f32x4){0.f, 0.f, 0.f, 0.f};

    const short* wptr = (const short*)Wsw + ((size_t)(g * 4 + wave) * 4096 + lane) * 8;

    short8 bcur[8], bnxt[8];
    #pragma unroll
    for (int nt = 0; nt < 8; ++nt)
        bcur[nt] = *(const short8*)(wptr + (size_t)(nt * 8) * 512);

    #pragma unroll 1
    for (int ks = 0; ks < 8; ++ks) {
        if (ks < 7) {
            #pragma unroll
            for (int nt = 0; nt < 8; ++nt)
                bnxt[nt] = *(const short8*)(wptr + (size_t)(nt * 8 + ks + 1) * 512);
        }
        const short8 a0 = *(const short8*)(lds_a + l15 * 264 + ks * 32 + lg * 8);
        const short8 a1 = *(const short8*)(lds_a + (16 + l15) * 264 + ks * 32 + lg * 8);
        #pragma unroll
        for (int nt = 0; nt < 8; ++nt) {
            acc[0][nt] = __builtin_amdgcn_mfma_f32_16x16x32_bf16(a0, bcur[nt], acc[0][nt], 0, 0, 0);
            acc[1][nt] = __builtin_amdgcn_mfma_f32_16x16x32_bf16(a1, bcur[nt], acc[1][nt], 0, 0, 0);
        }
        #pragma unroll
        for (int nt = 0; nt < 8; ++nt) bcur[nt] = bnxt[nt];
    }

    // ---- epilogue: bias, LN stats (cross-wave via LDS), SiLU, store ----
    float gv[8], tv[8];
    #pragma unroll
    for (int nt = 0; nt < 8; ++nt) {
        const int col = wcol + nt * 16 + l15;
        const float bv = bias[g * 512 + col];
        gv[nt] = gamma[g * 512 + col];
        tv[nt] = beta[g * 512 + col];
        #pragma unroll
        for (int r = 0; r < 4; ++r) { acc[0][nt][r] += bv; acc[1][nt][r] += bv; }
    }

    __shared__ float red[32][4][2];   // [row][wave][sum, sumsq]
    #pragma unroll
    for (int mt = 0; mt < 2; ++mt)
        #pragma unroll
        for (int r = 0; r < 4; ++r) {
            float s = 0.f, q = 0.f;
            #pragma unroll
            for (int nt = 0; nt < 8; ++nt) { const float v = acc[mt][nt][r]; s += v; q += v * v; }
            #pragma unroll
            for (int m = 1; m < 16; m <<= 1) { s += __shfl_xor(s, m); q += __shfl_xor(q, m); }
            if (l15 == 0) {
                const int row = mt * 16 + lg * 4 + r;
                red[row][wave][0] = s;
                red[row][wave][1] = q;
            }
        }
    __syncthreads();

    __shared__ float mu_s[32], ri_s[32];
    if (threadIdx.x < 32) {
        const int row = threadIdx.x;
        const float s = red[row][0][0] + red[row][1][0] + red[row][2][0] + red[row][3][0];
        const float q = red[row][0][1] + red[row][1][1] + red[row][2][1] + red[row][3][1];
        const float mu  = s * (1.f / 512.f);
        const float var = q * (1.f / 512.f) - mu * mu;
        mu_s[row] = mu;
        ri_s[row] = rsqrtf(var + 1e-5f);
    }
    __syncthreads();

    #pragma unroll
    for (int mt = 0; mt < 2; ++mt)
        #pragma unroll
        for (int r = 0; r < 4; ++r) {
            const int row = mt * 16 + lg * 4 + r;
            const float mu = mu_s[row];
            const float ri = ri_s[row];
            float* orow = out + ((size_t)(rowbase + row) * 4 + g) * 512 + wcol;
            #pragma unroll
            for (int nt = 0; nt < 8; ++nt) {
                const float h  = acc[mt][nt][r];
                const float hn = (h - mu) * ri * gv[nt] + tv[nt];
                orow[nt * 16 + l15] = hn / (1.f + __expf(-hn));
            }
        }
}

// ---------------------------------------------------------------------------
extern "C" void kernel_launch(void* const* d_in, const int* in_sizes, int n_in,
                              void* d_out, int out_size, void* d_ws, size_t ws_size,
                              hipStream_t stream) {
    const int*   feats  = (const int*)d_in[0];
    const float* tables = (const float*)d_in[1];
    const float* W      = (const float*)d_in[2];
    const float* bias   = (const float*)d_in[3];
    const float* gamma  = (const float*)d_in[4];
    const float* beta   = (const float*)d_in[5];
    float* out = (float*)d_out;

    __hip_bfloat16* Wsw = (__hip_bfloat16*)d_ws;   // 1 MB

    wprep_kernel<<<dim3(2048), dim3(256), 0, stream>>>(W, Wsw);
    fused_pool_gemm_ln<<<dim3(128, 4), dim3(256), 0, stream>>>(
        feats, tables, Wsw, bias, gamma, beta, out);
}